// Round 1
// 196.950 us; speedup vs baseline: 1.0152x; 1.0152x over previous
//
#include <hip/hip_runtime.h>
#include <hip/hip_bf16.h>

#define DD 128
#define NPTS 8192
#define BBATCH 32
#define BK 64
#define LAM 0.01f

typedef __attribute__((ext_vector_type(8))) short bf16x8;
typedef __attribute__((ext_vector_type(16))) float f32x16;

__device__ __forceinline__ unsigned f2bf_u(float f) {
    unsigned u = __builtin_bit_cast(unsigned, f);
    return (u + 0x7FFFu + ((u >> 16) & 1u)) >> 16;
}
__device__ __forceinline__ float bf2f(unsigned short u) {
    unsigned v = ((unsigned)u) << 16;
    return __builtin_bit_cast(float, v);
}
__device__ __forceinline__ int swz(int d) { return ((d >> 2) ^ d) & 7; }

// Kernel 1: per (batch, k-chunk) partial Gram via bf16 MFMA.
// 512 threads / 8 waves, 32x64 output slab per wave. Single-barrier ping-pong
// LDS; loads for t+1 issue before the MFMA section so the barrier's vmcnt
// drain is covered. Epilogue reduction restaged to a single barrier (XT is
// free after the loop: 8 planes x 512 floats = 16 KB fits the 32 KB buffer).
template<int P>
__global__ __launch_bounds__(512, 4) void gram_stats(
    const float* __restrict__ x, unsigned short* __restrict__ Spart,
    float* __restrict__ CSpart, float* __restrict__ KDpart)
{
    __shared__ short XT[2][DD * BK];   // ping-pong, 2 x 16 KB
    constexpr int rowsPerBlk = NPTS / P;
    constexpr int T = rowsPerBlk / BK;

    const int blk = blockIdx.x;
    const int b   = blk & 31;
    const int kc  = blk >> 5;
    const int k0g = kc * rowsPerBlk;
    const float* xb = x + (size_t)b * NPTS * DD;

    const int tid    = threadIdx.x;
    const int lane   = tid & 63;
    const int wave   = tid >> 6;      // 0..7
    const int dg     = tid & 31;      // d-group: owns d = 4*dg+i
    const int rowgrp = tid >> 5;      // 0..15: owns k-rows rowgrp*4 + r
    const int chunk  = rowgrp >> 1;   // k>>3 of owned rows
    const int wr32   = (wave & 3) * 32;
    const int wc64   = (wave >> 2) * 64;

    f32x16 acc0 = {}; f32x16 acc1 = {};
    float csum[4] = {0.f, 0.f, 0.f, 0.f};
    float kdot[4] = {0.f, 0.f, 0.f, 0.f};
    float4 R0, R1, R2, R3;

    auto issueLoads = [&](int kt) {
        const float4* s = (const float4*)(xb + (size_t)(k0g + kt + rowgrp * 4) * DD) + dg;
        R0 = s[0]; R1 = s[32]; R2 = s[64]; R3 = s[96];
    };
    auto convertStore = [&](int buf) {
        float x00 = __shfl(R0.x, lane & 32);
        float x01 = __shfl(R1.x, lane & 32);
        float x02 = __shfl(R2.x, lane & 32);
        float x03 = __shfl(R3.x, lane & 32);
        float e0[4] = {R0.x, R0.y, R0.z, R0.w};
        float e1[4] = {R1.x, R1.y, R1.z, R1.w};
        float e2[4] = {R2.x, R2.y, R2.z, R2.w};
        float e3[4] = {R3.x, R3.y, R3.z, R3.w};
        short* Xb = XT[buf];
        #pragma unroll
        for (int i = 0; i < 4; ++i) {
            csum[i] += e0[i] + e1[i] + e2[i] + e3[i];
            kdot[i] += x00 * e0[i] + x01 * e1[i] + x02 * e2[i] + x03 * e3[i];
            const int d = 4 * dg + i;
            unsigned u0 = f2bf_u(e0[i]) | (f2bf_u(e1[i]) << 16);
            unsigned u1 = f2bf_u(e2[i]) | (f2bf_u(e3[i]) << 16);
            const int addr = d * BK + ((chunk ^ swz(d)) * 8) + (rowgrp & 1) * 4;
            uint2 v; v.x = u0; v.y = u1;
            *(uint2*)(Xb + addr) = v;
        }
    };

    issueLoads(0);
    convertStore(0);
    __syncthreads();

    for (int t = 0; t < T; ++t) {
        if (t + 1 < T) issueLoads((t + 1) * BK);   // in flight across MFMA section
        const short* Xb = XT[t & 1];
        #pragma unroll
        for (int ks = 0; ks < BK / 16; ++ks) {
            const int cb = ks * 2 + (lane >> 5);
            const int m = lane & 31;
            const int ad = wr32 + m, b0d = wc64 + m, b1d = wc64 + 32 + m;
            bf16x8 a  = *(const bf16x8*)(Xb + ad  * BK + ((cb ^ swz(ad))  * 8));
            bf16x8 b0 = *(const bf16x8*)(Xb + b0d * BK + ((cb ^ swz(b0d)) * 8));
            bf16x8 b1 = *(const bf16x8*)(Xb + b1d * BK + ((cb ^ swz(b1d)) * 8));
            acc0 = __builtin_amdgcn_mfma_f32_32x32x16_bf16(a, b0, acc0, 0, 0, 0);
            acc1 = __builtin_amdgcn_mfma_f32_32x32x16_bf16(a, b1, acc1, 0, 0, 0);
        }
        if (t + 1 < T) convertStore((t + 1) & 1);
        __syncthreads();   // one barrier/iter: protects both ping-pong halves
    }

    // write partial Gram bf16 (C/D: col=lane&31, row=(r&3)+8*(r>>2)+4*(lane>>5))
    unsigned short* Sp = Spart + ((size_t)b * P + kc) * (DD * DD);
    const int colLane = lane & 31;
    const int rowHw = 4 * (lane >> 5);
    #pragma unroll
    for (int r = 0; r < 16; ++r) {
        const int row = wr32 + (r & 3) + 8 * (r >> 2) + rowHw;
        Sp[row * DD + wc64 + colLane]      = (unsigned short)f2bf_u(acc0[r]);
        Sp[row * DD + wc64 + 32 + colLane] = (unsigned short)f2bf_u(acc1[r]);
    }

    // block-reduce colsum / keydot: 8 planes staged at once, ONE barrier
    // (was 4x2 planes with 8 barriers). XT no longer read: 16 KB of 32 KB used.
    float* red = (float*)XT;
    #pragma unroll
    for (int i = 0; i < 4; ++i) {
        red[i * 512 + tid]       = csum[i];
        red[(4 + i) * 512 + tid] = kdot[i];
    }
    __syncthreads();
    if (tid < 64) {
        const int tt = tid & 31;
        const float* basep = red + ((tid < 32) ? 0 : 4 * 512);
        float* dst = ((tid < 32) ? CSpart : KDpart) + ((size_t)b * P + kc) * DD;
        #pragma unroll
        for (int i = 0; i < 4; ++i) {
            float s = 0.f;
            #pragma unroll
            for (int g = 0; g < 16; ++g) s += basep[i * 512 + g * 32 + tt];
            dst[4 * tt + i] = s;
        }
    }
}

// Kernel 2 (merged, was kernels 2+3): block (b, seg of 16 rows).
// Reduces CSpart/KDpart partials + computes keys/ranks locally (removes the
// old 32-block keys_ranks launch, its graph gap, and the csOut/rankOut
// round-trip), then reduces bf16 partial Grams, applies mean/ridge fixup,
// and scatters rows to their ranked position.
template<int P>
__global__ __launch_bounds__(512) void reduce_scatter(
    const unsigned short* __restrict__ Spart, const float* __restrict__ CSpart,
    const float* __restrict__ KDpart, float* __restrict__ out)
{
    __shared__ float csh[DD];
    __shared__ float key[DD];
    __shared__ int rk[16];
    const int b   = blockIdx.x;
    const int seg = blockIdx.y;       // 0..7, 16 rows each
    const int tid = threadIdx.x;      // 512

    // fp32 reduce of column sums / key dots over P partials (threads 0..127)
    float kd = 0.f;
    if (tid < DD) {
        float s = 0.f;
        #pragma unroll
        for (int p = 0; p < P; ++p) {
            s  += CSpart[((size_t)b * P + p) * DD + tid];
            kd += KDpart[((size_t)b * P + p) * DD + tid];
        }
        csh[tid] = s;
    }

    // accumulate bf16 partial Grams for our 16 rows (overlaps with the above)
    const int base = seg * (16 * DD) + tid * 4;
    float a0 = 0.f, a1 = 0.f, a2 = 0.f, a3 = 0.f;
    #pragma unroll
    for (int p = 0; p < P; ++p) {
        uint2 v = *(const uint2*)(Spart + ((size_t)b * P + p) * (DD * DD) + base);
        a0 += bf2f((unsigned short)(v.x & 0xFFFFu));
        a1 += bf2f((unsigned short)(v.x >> 16));
        a2 += bf2f((unsigned short)(v.y & 0xFFFFu));
        a3 += bf2f((unsigned short)(v.y >> 16));
    }
    __syncthreads();                  // csh[0] visible to all key writers
    if (tid < DD) {
        key[tid] = (kd - csh[tid] * csh[0] * (1.f / NPTS)) * (1.f / (NPTS - 1))
                 + ((tid == 0) ? LAM : 0.f);
    }
    __syncthreads();
    if (tid < 16) {
        const int j0 = seg * 16 + tid;
        const float k = key[j0];
        int r = 0;
        #pragma unroll 8
        for (int j = 0; j < DD; ++j) {
            const float kj = key[j];
            r += (kj < k) || (kj == k && j < j0);
        }
        rk[tid] = r;
    }
    __syncthreads();

    const int row = seg * 16 + (tid >> 5);
    const int c0  = (tid & 31) * 4;
    const float ci = csh[row];
    const float invN = 1.f / NPTS, invNm1 = 1.f / (NPTS - 1);
    float4 v;
    v.x = (a0 - ci * csh[c0 + 0] * invN) * invNm1 + ((row == c0 + 0) ? LAM : 0.f);
    v.y = (a1 - ci * csh[c0 + 1] * invN) * invNm1 + ((row == c0 + 1) ? LAM : 0.f);
    v.z = (a2 - ci * csh[c0 + 2] * invN) * invNm1 + ((row == c0 + 2) ? LAM : 0.f);
    v.w = (a3 - ci * csh[c0 + 3] * invN) * invNm1 + ((row == c0 + 3) ? LAM : 0.f);
    float* o = out + (size_t)b * DD * DD + (size_t)rk[tid >> 5] * DD + c0;
    *(float4*)o = v;
}

template<int P>
static void launch_all(const float* x, float* out, void* d_ws, hipStream_t stream)
{
    size_t nS = (size_t)BBATCH * P * DD * DD;           // shorts
    unsigned short* Spart = (unsigned short*)d_ws;
    float* CSpart = (float*)(Spart + nS);
    float* KDpart = CSpart + (size_t)BBATCH * P * DD;

    gram_stats<P><<<dim3(32 * P), dim3(512), 0, stream>>>(x, Spart, CSpart, KDpart);
    reduce_scatter<P><<<dim3(BBATCH, 8), dim3(512), 0, stream>>>(Spart, CSpart, KDpart, out);
}

extern "C" void kernel_launch(void* const* d_in, const int* in_sizes, int n_in,
                              void* d_out, int out_size, void* d_ws, size_t ws_size,
                              hipStream_t stream)
{
    const float* x = (const float*)d_in[0];
    float* out = (float*)d_out;

    auto need = [](int P) {
        return (size_t)BBATCH * P * DD * DD * sizeof(unsigned short)
             + (size_t)BBATCH * P * 2 * DD * sizeof(float);
    };
    if (need(16) <= ws_size)      launch_all<16>(x, out, d_ws, stream);
    else                          launch_all<8>(x, out, d_ws, stream);
}